// Round 3
// 3995.613 us; speedup vs baseline: 1.4198x; 1.4198x over previous
//
#include <hip/hip_runtime.h>
#include <math.h>

#define CB 64
#define CT 512
#define CD 256
#define CH 1024
#define CV 32000

// ---- phase-A LDS layouts (unchanged from baseline) ----
#define XS_STRIDE 280
#define WL_STRIDE 284
// ---- RNN h-tile layout: 8 rows x 1024 K; K split in 64 chunks of 16 floats
// padded to 20 (20*kc mod 32 is a bijection over kc&7 -> conflict-free
// ds_read_b128 across the 8 kg lanes; the 8 cg lanes share addresses and
// broadcast for free).
#define HR_ROW 1280

#define FLAG_STRIDE 32   // uints (128 B) per flag

typedef float f32x4 __attribute__((ext_vector_type(4)));

// ============ agent-scope (sc0 sc1, via L3) exchange primitives ============
// Byte-equivalent to the baseline's proven protocol: stores write through L2
// to the die-level coherence point; loads bypass L1+L2. Producer order:
// h stores -> s_waitcnt vmcnt(0) -> flag store. Consumer: poll flag, then
// load h. No wbl2/inv needed on this path.
__device__ __forceinline__ unsigned ld_flag(const unsigned* p) {
  unsigned v;
  asm volatile("global_load_dword %0, %1, off sc0 sc1\n\ts_waitcnt vmcnt(0)"
               : "=v"(v) : "v"(p) : "memory");
  return v;
}
__device__ __forceinline__ void st_flag(unsigned* p, unsigned v) {
  asm volatile("global_store_dword %0, %1, off sc0 sc1" :: "v"(p), "v"(v) : "memory");
}
__device__ __forceinline__ void st_h4(float* p, f32x4 v) {
  asm volatile("global_store_dwordx4 %0, %1, off sc0 sc1" :: "v"(p), "v"(v) : "memory");
}
__device__ __forceinline__ void ld4_h(const float* p0, const float* p1,
                                      const float* p2, const float* p3,
                                      f32x4& a0, f32x4& a1, f32x4& a2, f32x4& a3) {
  asm volatile(
    "global_load_dwordx4 %0, %4, off sc0 sc1\n\t"
    "global_load_dwordx4 %1, %5, off sc0 sc1\n\t"
    "global_load_dwordx4 %2, %6, off sc0 sc1\n\t"
    "global_load_dwordx4 %3, %7, off sc0 sc1\n\t"
    "s_waitcnt vmcnt(0)"
    : "=&v"(a0), "=&v"(a1), "=&v"(a2), "=&v"(a3)
    : "v"(p0), "v"(p1), "v"(p2), "v"(p3)
    : "memory");
}

// Grid-wide fenced barrier (chunk boundaries only): release store emits
// wbl2; acquire __threadfence emits buffer_inv -> cached xwbuf writes become
// visible. 256 flags polled by waves 0..3.
__device__ __forceinline__ void grid_barrier_fenced(unsigned* gbar, int bid, unsigned target) {
  __syncthreads();
  const int w = threadIdx.x >> 6, lane = threadIdx.x & 63;
  if (threadIdx.x == 0)
    __hip_atomic_store(gbar + (size_t)bid * FLAG_STRIDE, target,
                       __ATOMIC_RELEASE, __HIP_MEMORY_SCOPE_AGENT);
  if (w < 4) {
    const unsigned* f = gbar + (size_t)(w * 64 + lane) * FLAG_STRIDE;
    int spin = 0;
    unsigned v;
    do {
      v = __hip_atomic_load(f, __ATOMIC_RELAXED, __HIP_MEMORY_SCOPE_AGENT);
    } while (__any((int)(v < target)) && ++spin < (1 << 25));
  }
  __threadfence();
  __syncthreads();
}

extern "C" __global__ void __launch_bounds__(512, 1)
rnn_scan_kernel(const float* __restrict__ x, const float* __restrict__ W,
                const float* __restrict__ U, const float* __restrict__ bb,
                float* __restrict__ hbuf, float* __restrict__ xwbuf,
                unsigned* __restrict__ gbar, unsigned* __restrict__ sbar, int Tc)
{
  __shared__ float sA[18432];            // union: x-tiles (phase A) | h-tile (RNN, 8*1280)
  __shared__ float sB[18432];            // W-slice (phase A); unused during RNN (U in VGPRs)
  __shared__ float red[8][8][40];        // cross-wave K partials (40-stride: 2-way banks max)

  const int tid  = threadIdx.x;
  const int bid  = blockIdx.x;
  const int w    = tid >> 6;             // wave 0..7
  const int lane = tid & 63;

  // ---- RNN group mapping: 8 groups x 32 blocks. Group xg owns batch rows
  // 8*xg..8*xg+7; block sl within group owns 32 H-columns. ----
  const int xg = bid >> 5;
  const int sl = bid & 31;
  const int c0 = sl << 5;
  unsigned* myflag = sbar + (size_t)(xg * 32 + sl) * FLAG_STRIDE;
  const unsigned* fbase = sbar + (size_t)(xg * 32) * FLAG_STRIDE;

  // ---- phase-A (xW precompute) mapping: by blockIdx, unchanged ----
  const int r    = bid >> 6;
  const int q    = bid & 63;
  const int tsub = q >> 4, acg = q & 15;
  const int a_tw = w >> 1, a_jh = w & 1;
  const int a_kg = lane >> 5;
  const int a_pi = (lane >> 3) & 3;
  const int a_pj = lane & 7;
  const int a_jl = a_jh * 32 + a_pj * 4;
  const int a_jglob = acg * 64 + a_jl;
  float4 a_bias = *(const float4*)(bb + a_jglob);

  // ---- RNN compute lane mapping ----
  const int kg  = lane >> 3;             // 0..7: K-sub-chunk within wave
  const int ccg = lane & 7;              // 0..7: 4-col group
  const int kc  = w * 8 + kg;            // 0..63: 16-wide K chunk
  const int jb  = c0 + ccg * 4;          // global col base (4 cols)

  // ===== U fragment -> registers (64 VGPRs): fixed for the whole kernel =====
  // Thread owns U[kc*16 .. kc*16+15][jb .. jb+3]. No LDS U, no per-step U
  // reads: per-step LDS traffic is h-only.
  f32x4 ureg[16];
  #pragma unroll
  for (int k = 0; k < 16; ++k)
    ureg[k] = *(const f32x4*)(U + (size_t)(kc * 16 + k) * CH + jb);

  const int nchunk = CT / Tc;
  const int tquarter = Tc >> 2;
  unsigned gep = 0;

  for (int chunk = 0; chunk < nchunk; ++chunk) {
    // ===== stage W slice (64 cols, transposed) into sB =====
    __syncthreads();
    for (int f = tid; f < 4096; f += 512) {
      int kk = f >> 4, seg = f & 15;
      float4 v = *(const float4*)(W + (size_t)kk * CH + acg * 64 + seg * 4);
      float* wrow = sB + (size_t)(seg * 4) * WL_STRIDE + kk + (seg & 7) * 4;
      wrow[0 * WL_STRIDE] = v.x;
      wrow[1 * WL_STRIDE] = v.y;
      wrow[2 * WL_STRIDE] = v.z;
      wrow[3 * WL_STRIDE] = v.w;
    }

    // ===== phase A: xwbuf[t][b][j] = x[b,t,:] @ W + bias =====
    for (int tb = 0; tb < tquarter; tb += 4) {
      int nt = tquarter - tb; if (nt > 4) nt = 4;
      __syncthreads();
      for (int f = tid; f < nt * 1024; f += 512) {
        int tw = f >> 10, rem = f & 1023;
        int row = rem >> 6, col = (rem & 63) * 4;
        int t = chunk * Tc + tsub * tquarter + tb + tw;
        float4 v = *(const float4*)(x + ((size_t)(r * 16 + row) * CT + t) * CD + col);
        *(float4*)(sA + (size_t)(tw * 16 + row) * XS_STRIDE + col + ((row >> 2) & 3) * 8) = v;
      }
      __syncthreads();
      if (a_tw < nt) {
        int tloc = tsub * tquarter + tb + a_tw;
        float acc[4][4];
        #pragma unroll
        for (int i2 = 0; i2 < 4; ++i2)
          #pragma unroll
          for (int j2 = 0; j2 < 4; ++j2) acc[i2][j2] = 0.f;
        const float* xbase = sA + (size_t)(a_tw * 16 + a_pi * 4) * XS_STRIDE + a_kg * 128 + a_pi * 8;
        const float* wbase = sB + (size_t)a_jl * WL_STRIDE + a_kg * 128 + a_pj * 4;
        #pragma unroll 2
        for (int u = 0; u < 128; u += 4) {
          float4 ha[4], wb[4];
          #pragma unroll
          for (int di = 0; di < 4; ++di) ha[di] = *(const float4*)(xbase + (size_t)di * XS_STRIDE + u);
          #pragma unroll
          for (int dj = 0; dj < 4; ++dj) wb[dj] = *(const float4*)(wbase + (size_t)dj * WL_STRIDE + u);
          #pragma unroll
          for (int di = 0; di < 4; ++di)
            #pragma unroll
            for (int dj = 0; dj < 4; ++dj)
              acc[di][dj] += ha[di].x * wb[dj].x + ha[di].y * wb[dj].y
                           + ha[di].z * wb[dj].z + ha[di].w * wb[dj].w;
        }
        #pragma unroll
        for (int di = 0; di < 4; ++di)
          #pragma unroll
          for (int dj = 0; dj < 4; ++dj)
            acc[di][dj] += __shfl_xor(acc[di][dj], 32, 64);
        if (a_kg == 0) {
          size_t obase = (size_t)tloc * (CB * CH) + (size_t)(r * 16 + a_pi * 4) * CH + a_jglob;
          #pragma unroll
          for (int di = 0; di < 4; ++di) {
            float4 o;
            o.x = acc[di][0] + a_bias.x;
            o.y = acc[di][1] + a_bias.y;
            o.z = acc[di][2] + a_bias.z;
            o.w = acc[di][3] + a_bias.w;
            *(float4*)(xwbuf + obase + (size_t)di * CH) = o;
          }
        }
      }
      __syncthreads();
    }

    // xwbuf chunk visible grid-wide (wbl2 + inv)
    grid_barrier_fenced(gbar, bid, ++gep);

    // ===== RNN steps for this chunk =====
    for (int tc = 0; tc < Tc; ++tc) {
      const int g = chunk * Tc + tc;
      const float* hb_r = hbuf + (size_t)(g & 1) * (CB * CH);
      float*       hb_w = hbuf + (size_t)((g & 1) ^ 1) * (CB * CH);

      // prefetch combine operand (stable since chunk fence); latency hides
      // under poll + stage + compute.
      f32x4 zxw;
      if (w == 0) {
        zxw = *(const f32x4*)(xwbuf + (size_t)tc * (CB * CH)
                              + (size_t)(xg * 8 + (lane >> 3)) * CH + c0 + (lane & 7) * 4);
      }

      if (g > 0) {
        // -- wave0 polls its group's 32 step flags (h(g-1) flagged g) --
        if (w == 0) {
          const unsigned* f = fbase + (size_t)(lane & 31) * FLAG_STRIDE;
          int spin = 0;
          unsigned v;
          do { v = ld_flag(f); } while (__any((int)(v < (unsigned)g)) && ++spin < (1 << 26));
        }
        __syncthreads();

        // -- stage h(g-1): 8 rows x 1024 (32 KB), agent-scope 16B loads --
        {
          const float* hr = hb_r + (size_t)(xg << 3) * CH;
          const int i0 = tid, i1 = tid + 512, i2 = tid + 1024, i3 = tid + 1536;
          const float* p0 = hr + ((size_t)(i0 >> 8) << 10) + ((i0 & 255) << 2);
          const float* p1 = hr + ((size_t)(i1 >> 8) << 10) + ((i1 & 255) << 2);
          const float* p2 = hr + ((size_t)(i2 >> 8) << 10) + ((i2 & 255) << 2);
          const float* p3 = hr + ((size_t)(i3 >> 8) << 10) + ((i3 & 255) << 2);
          f32x4 a0, a1, a2, a3;
          ld4_h(p0, p1, p2, p3, a0, a1, a2, a3);
          *(f32x4*)(sA + (i0 >> 8) * HR_ROW + ((i0 & 255) >> 2) * 20 + (i0 & 3) * 4) = a0;
          *(f32x4*)(sA + (i1 >> 8) * HR_ROW + ((i1 & 255) >> 2) * 20 + (i1 & 3) * 4) = a1;
          *(f32x4*)(sA + (i2 >> 8) * HR_ROW + ((i2 & 255) >> 2) * 20 + (i2 & 3) * 4) = a2;
          *(f32x4*)(sA + (i3 >> 8) * HR_ROW + ((i3 & 255) >> 2) * 20 + (i3 & 3) * 4) = a3;
        }
        __syncthreads();

        // -- partials: acc[8 rows][4 cols] over this thread's 16-wide K chunk --
        {
          const float* hbase = sA + kc * 20;
          f32x4 acc[8];
          #pragma unroll
          for (int di = 0; di < 8; ++di) acc[di] = (f32x4){0.f, 0.f, 0.f, 0.f};
          #pragma unroll
          for (int us = 0; us < 4; ++us) {
            const int u = us * 4;
            const f32x4 u0 = ureg[u + 0], u1 = ureg[u + 1], u2 = ureg[u + 2], u3 = ureg[u + 3];
            #pragma unroll
            for (int di = 0; di < 8; ++di) {
              const f32x4 hv = *(const f32x4*)(hbase + di * HR_ROW + u);
              acc[di] += hv.x * u0 + hv.y * u1 + hv.z * u2 + hv.w * u3;
            }
          }
          // reduce over kg lanes (8 apart) -> all lanes hold wave partial
          #pragma unroll
          for (int di = 0; di < 8; ++di) {
            #pragma unroll
            for (int m = 8; m < 64; m <<= 1) {
              acc[di].x += __shfl_xor(acc[di].x, m, 64);
              acc[di].y += __shfl_xor(acc[di].y, m, 64);
              acc[di].z += __shfl_xor(acc[di].z, m, 64);
              acc[di].w += __shfl_xor(acc[di].w, m, 64);
            }
          }
          if (kg == 0) {
            #pragma unroll
            for (int di = 0; di < 8; ++di)
              *(f32x4*)&red[w][di][ccg * 4] = acc[di];
          }
        }
        __syncthreads();
      }

      // -- combine + tanh + agent store + flag (wave 0; 64 lanes = 64 f4) --
      if (w == 0) {
        const int i = lane >> 3, j4 = lane & 7;
        f32x4 z = zxw;
        if (g > 0) {
          #pragma unroll
          for (int ww = 0; ww < 8; ++ww) {
            const f32x4 rv = *(const f32x4*)&red[ww][i][j4 * 4];
            z += rv;
          }
        }
        f32x4 o;
        o.x = tanhf(z.x); o.y = tanhf(z.y); o.z = tanhf(z.z); o.w = tanhf(z.w);
        st_h4(hb_w + (size_t)(xg * 8 + i) * CH + c0 + j4 * 4, o);
        asm volatile("s_waitcnt vmcnt(0)" ::: "memory");   // h committed before flag
        if (lane == 0) st_flag(myflag, (unsigned)(g + 1));
      }
      // no end-of-step barrier: next iteration's post-poll __syncthreads
      // (or the chunk barrier) is the join point; waves 1-7 only touch sA
      // after sync#1, which wave0 reaches post-combine. A fast block can't
      // overwrite h a slow block still needs: its step-(g+1) h store happens
      // only after it saw ALL group flags >= g+1, i.e. every block finished
      // staging+compute of step g.
    }

    // protect xwbuf slots from next chunk's phase A until every block has
    // finished its last combine read of this chunk.
    if (chunk + 1 < nchunk) grid_barrier_fenced(gbar, bid, ++gep);
  }
}

// ===== logits: out[64,32000] = hT @ Wd + bd ; one wave computes a 64x64 tile =====
extern "C" __global__ void __launch_bounds__(64, 1)
logits_kernel(const float* __restrict__ hfin, const float* __restrict__ Wd,
              const float* __restrict__ bd, float* __restrict__ out)
{
  __shared__ float al[64][68];   // hT chunk, transposed: al[k][row]
  __shared__ float wl[64][68];   // Wd chunk: wl[k][col]
  const int n0 = blockIdx.x * 64;
  const int lane = threadIdx.x;
  const int pi = lane >> 3, pj = lane & 7;
  float acc[8][8];
  #pragma unroll
  for (int a = 0; a < 8; ++a)
    #pragma unroll
    for (int bq = 0; bq < 8; ++bq) acc[a][bq] = 0.f;

  for (int k0 = 0; k0 < CH; k0 += 64) {
    __syncthreads();
    #pragma unroll
    for (int p = 0; p < 16; ++p) {
      int row = p * 4 + (lane >> 4);
      int seg = lane & 15;
      float4 v = *(const float4*)(hfin + (size_t)row * CH + k0 + seg * 4);
      al[seg * 4 + 0][row] = v.x;
      al[seg * 4 + 1][row] = v.y;
      al[seg * 4 + 2][row] = v.z;
      al[seg * 4 + 3][row] = v.w;
    }
    #pragma unroll
    for (int p = 0; p < 16; ++p) {
      int f = p * 64 + lane;
      int kk = f >> 4, seg = f & 15;
      *(float4*)&wl[kk][seg * 4] = *(const float4*)(Wd + (size_t)(k0 + kk) * CV + n0 + seg * 4);
    }
    __syncthreads();
    #pragma unroll 2
    for (int kk = 0; kk < 64; ++kk) {
      float av[8], bv[8];
      *(float4*)&av[0] = *(const float4*)&al[kk][pi * 8];
      *(float4*)&av[4] = *(const float4*)&al[kk][pi * 8 + 4];
      *(float4*)&bv[0] = *(const float4*)&wl[kk][pj * 8];
      *(float4*)&bv[4] = *(const float4*)&wl[kk][pj * 8 + 4];
      #pragma unroll
      for (int a = 0; a < 8; ++a)
        #pragma unroll
        for (int bq = 0; bq < 8; ++bq)
          acc[a][bq] += av[a] * bv[bq];
    }
  }
  float bdv[8];
  *(float4*)&bdv[0] = *(const float4*)(bd + n0 + pj * 8);
  *(float4*)&bdv[4] = *(const float4*)(bd + n0 + pj * 8 + 4);
  #pragma unroll
  for (int a = 0; a < 8; ++a) {
    int row = pi * 8 + a;
    float4 o0, o1;
    o0.x = acc[a][0] + bdv[0]; o0.y = acc[a][1] + bdv[1];
    o0.z = acc[a][2] + bdv[2]; o0.w = acc[a][3] + bdv[3];
    o1.x = acc[a][4] + bdv[4]; o1.y = acc[a][5] + bdv[5];
    o1.z = acc[a][6] + bdv[6]; o1.w = acc[a][7] + bdv[7];
    *(float4*)(out + (size_t)row * CV + n0 + pj * 8) = o0;
    *(float4*)(out + (size_t)row * CV + n0 + pj * 8 + 4) = o1;
  }
}

// ===== softmax in place over each row of out[64,32000] =====
extern "C" __global__ void __launch_bounds__(256)
softmax_kernel(float* __restrict__ out)
{
  __shared__ float red[256];
  const int row = blockIdx.x;
  const int tid = threadIdx.x;
  float* p = out + (size_t)row * CV;
  float m = -3.4e38f;
  for (int i = tid; i < CV; i += 256) m = fmaxf(m, p[i]);
  red[tid] = m;
  __syncthreads();
  for (int s = 128; s > 0; s >>= 1) {
    if (tid < s) red[tid] = fmaxf(red[tid], red[tid + s]);
    __syncthreads();
  }
  m = red[0];
  __syncthreads();
  float sum = 0.f;
  for (int i = tid; i < CV; i += 256) {
    float e = expf(p[i] - m);
    p[i] = e;
    sum += e;
  }
  red[tid] = sum;
  __syncthreads();
  for (int s = 128; s > 0; s >>= 1) {
    if (tid < s) red[tid] = red[tid] + red[tid + s];
    __syncthreads();
  }
  float inv = 1.f / red[0];
  for (int i = tid; i < CV; i += 256) p[i] *= inv;
}

// zero gbar (32 KB) + sbar (32 KB) = 16384 uints
extern "C" __global__ void init_ws(unsigned* p) {
  p[(size_t)blockIdx.x * 1024 + threadIdx.x] = 0u;
}

extern "C" void kernel_launch(void* const* d_in, const int* in_sizes, int n_in,
                              void* d_out, int out_size, void* d_ws, size_t ws_size,
                              hipStream_t stream) {
  const float* x  = (const float*)d_in[0];
  const float* W  = (const float*)d_in[1];
  const float* U  = (const float*)d_in[2];
  const float* bb = (const float*)d_in[3];
  const float* Wd = (const float*)d_in[4];
  const float* bd = (const float*)d_in[5];
  float* out = (float*)d_out;

  char* ws = (char*)d_ws;
  unsigned* gbar = (unsigned*)ws;                   // 32 KiB grid-barrier flags
  unsigned* sbar = (unsigned*)(ws + 32768);         // 32 KiB per-group step flags
  float* hbuf  = (float*)(ws + 65536);
  float* xwbuf = (float*)(ws + 65536 + (size_t)2 * CB * CH * sizeof(float));

  // largest xW chunk that fits the workspace (Tc divides 512, multiple of 4)
  const int cands[7] = {512, 256, 128, 64, 32, 16, 8};
  int Tc = 4;
  for (int ci = 0; ci < 7; ++ci) {
    size_t need = 65536 + (size_t)2 * CB * CH * 4 + (size_t)cands[ci] * CB * CH * 4;
    if (need <= ws_size) { Tc = cands[ci]; break; }
  }

  hipLaunchKernelGGL(init_ws, dim3(16), dim3(1024), 0, stream, (unsigned*)ws);

  void* args[9];
  args[0] = (void*)&x;     args[1] = (void*)&W;     args[2] = (void*)&U;
  args[3] = (void*)&bb;    args[4] = (void*)&hbuf;  args[5] = (void*)&xwbuf;
  args[6] = (void*)&gbar;  args[7] = (void*)&sbar;  args[8] = (void*)&Tc;
  hipLaunchCooperativeKernel((void*)rnn_scan_kernel, dim3(256), dim3(512), args, 0, stream);

  // final h state lives in hbuf[0] (T=512 even)
  hipLaunchKernelGGL(logits_kernel, dim3(CV / 64), dim3(64), 0, stream, hbuf, Wd, bd, out);
  hipLaunchKernelGGL(softmax_kernel, dim3(CB), dim3(256), 0, stream, out);
}